// Round 8
// baseline (610.087 us; speedup 1.0000x reference)
//
#include <hip/hip_runtime.h>
#include <math.h>

constexpr int cB = 2, cC = 64, cH = 48, cW = 48, cL = 48 * 48;
constexpr int cBR = 128, cDI = 128, cNS = 16, cRK = 4, cK = 4;
constexpr float cEPS = 1e-5f;
constexpr int NCH = 32;          // scan chunks
constexpr int CHL = cL / NCH;    // 72 positions per chunk
constexpr int KTOT = 5824;       // 9*640 conv + 64 shortcut
constexpr unsigned int SCAN_BLOCKS = 64 * NCH;   // 2048 = exactly co-resident (8/CU x 256 CU)

typedef unsigned short u16;
typedef unsigned int u32;
typedef short s16x8 __attribute__((ext_vector_type(8)));
typedef float f32x4 __attribute__((ext_vector_type(4)));

__device__ __forceinline__ float bnrelu(float v, float g, float b) {
    float y = v * (g * rsqrtf(1.0f + cEPS)) + b;
    return y > 0.f ? y : 0.f;
}
__device__ __forceinline__ float silu(float v) {
    return v / (1.f + __expf(-v));
}
__device__ __forceinline__ u16 f2bf(float f) {
    u32 u = __float_as_uint(f);
    u = (u + 0x7fffu + ((u >> 16) & 1u)) >> 16;
    return (u16)u;
}
__device__ __forceinline__ s16x8 cvt8(const float* p) {
    s16x8 r;
#pragma unroll
    for (int i = 0; i < 8; i++) r[i] = (short)f2bf(p[i]);
    return r;
}
// sum over each aligned 16-lane row via DPP (full-rate VALU, no DS pipe)
__device__ __forceinline__ float row_sum16(float v) {
    v += __int_as_float(__builtin_amdgcn_update_dpp(0, __float_as_int(v), 0xB1, 0xF, 0xF, true));  // quad xor1
    v += __int_as_float(__builtin_amdgcn_update_dpp(0, __float_as_int(v), 0x4E, 0xF, 0xF, true));  // quad xor2
    v += __int_as_float(__builtin_amdgcn_update_dpp(0, __float_as_int(v), 0x124, 0xF, 0xF, true)); // row_ror:4
    v += __int_as_float(__builtin_amdgcn_update_dpp(0, __float_as_int(v), 0x128, 0xF, 0xF, true)); // row_ror:8
    return v;
}

// ------- MERGED pools + weight prep + dwk repack + c1k pack (one launch) -------
// blk: [0,288) pool5 | [288,360) pool9 | [360,488) gmean | [488,1944) w8
//      [1944,2008) wcat | [2008,2072) ipk | [2072,2144) xpk | [2144,2149) dwk | [2149,2213) c1k
__global__ void __launch_bounds__(256) k_pp(const float* __restrict__ x,
                                            float* __restrict__ pool5, float* __restrict__ pool9,
                                            float* __restrict__ gmean,
                                            const float* __restrict__ cw, const float* __restrict__ scw,
                                            const float* __restrict__ s0w, const float* __restrict__ s1w,
                                            const float* __restrict__ ipw, const float* __restrict__ xpw,
                                            const float* __restrict__ dww,
                                            const float* __restrict__ s2w, const float* __restrict__ s3w,
                                            u16* __restrict__ w8, u16* __restrict__ wcat,
                                            u16* __restrict__ ipk, u16* __restrict__ xpk,
                                            float* __restrict__ dwk, u16* __restrict__ c1k) {
    __shared__ float sm[4];
    int blk = blockIdx.x;
    int t = threadIdx.x;
    if (blk < 288) {
        int idx = blk * 256 + t;   // 5x5 s2 p2 -> 24x24
        int w = idx % 24, h = (idx / 24) % 24, bc = idx / 576;
        const float* p = x + bc * cL;
        float s = 0.f;
        for (int kh = 0; kh < 5; kh++) {
            int hh = h * 2 - 2 + kh; if (hh < 0 || hh >= cH) continue;
            for (int kw = 0; kw < 5; kw++) {
                int ww = w * 2 - 2 + kw; if (ww < 0 || ww >= cW) continue;
                s += p[hh * cW + ww];
            }
        }
        pool5[idx] = s * (1.f / 25.f);
    } else if (blk < 360) {
        int idx = (blk - 288) * 256 + t;   // 9x9 s4 p4 -> 12x12
        int w = idx % 12, h = (idx / 12) % 12, bc = idx / 144;
        const float* p = x + bc * cL;
        float s = 0.f;
        for (int kh = 0; kh < 9; kh++) {
            int hh = h * 4 - 4 + kh; if (hh < 0 || hh >= cH) continue;
            for (int kw = 0; kw < 9; kw++) {
                int ww = w * 4 - 4 + kw; if (ww < 0 || ww >= cW) continue;
                s += p[hh * cW + ww];
            }
        }
        pool9[idx] = s * (1.f / 81.f);
    } else if (blk < 488) {
        int bc = blk - 360;
        const float* p = x + bc * cL;
        float s = 0.f;
        for (int i = t; i < cL; i += 256) s += p[i];
        for (int m = 32; m > 0; m >>= 1) s += __shfl_down(s, m);
        if ((t & 63) == 0) sm[t >> 6] = s;
        __syncthreads();
        if (t == 0) gmean[bc] = (sm[0] + sm[1] + sm[2] + sm[3]) * (1.f / cL);
    } else if (blk < 1944) {
        int idx = (blk - 488) * 256 + t;  // < 64*KTOT exactly
        int o = idx / KTOT, kx = idx % KTOT;
        float v;
        if (kx < 5760) { int tap = kx / 640, ch = kx % 640; v = cw[(o * 640 + ch) * 9 + tap]; }
        else v = scw[o * 64 + (kx - 5760)];
        w8[(((size_t)(kx >> 3) * 64) + o) * 8 + (kx & 7)] = f2bf(v);
    } else if (blk < 2008) {
        int idx = (blk - 1944) * 256 + t;
        int g = idx >> 13, r = idx & 8191;
        int o = r >> 6, c = r & 63;
        float v = (g ? s1w : s0w)[r];
        int kt = c >> 5, q = (c >> 3) & 3, j = c & 7, nt = o >> 4, ln = o & 15;
        wcat[(size_t)((((g * 2 + kt) * 4 + q) * 8 + nt) * 16 + ln) * 8 + j] = f2bf(v);
    } else if (blk < 2072) {
        int idx = (blk - 2008) * 256 + t;
        int o = idx >> 6, c = idx & 63;
        int kt = c >> 5, q = (c >> 3) & 3, j = c & 7, nt = o >> 4, ln = o & 15;
        ipk[(size_t)(((kt * 4 + q) * 16 + nt) * 16 + ln) * 8 + j] = f2bf(ipw[idx]);
    } else if (blk < 2144) {
        int idx = (blk - 2072) * 256 + t;
        int o = idx >> 7, d = idx & 127;
        int kt = d >> 5, q = (d >> 3) & 3, j = d & 7, nt = o >> 4, ln = o & 15;
        xpk[(size_t)(((kt * 4 + q) * 9 + nt) * 16 + ln) * 8 + j] = f2bf(xpw[idx]);
    } else if (blk < 2149) {
        int idx = (blk - 2144) * 256 + t;   // dwk[tap][ch] = dww[ch*9+tap], 1152 elems
        if (idx < 1152) {
            int tap = idx >> 7, ch = idx & 127;
            dwk[idx] = dww[ch * 9 + tap];
        }
    } else {
        int idx = (blk - 2149) * 256 + t;   // pack s2w/s3w for MFMA (like wcat)
        int g = idx >> 13, r = idx & 8191;
        int o = r >> 6, c = r & 63;
        float v = (g ? s3w : s2w)[r];
        int kt = c >> 5, q = (c >> 3) & 3, j = c & 7, nt = o >> 4, ln = o & 15;
        c1k[(size_t)((((g * 2 + kt) * 4 + q) * 8 + nt) * 16 + ln) * 8 + j] = f2bf(v);
    }
}

// ------- bn_relu + 1x1 conv (64->128) via MFMA tiles; gmean scalar path -------
// blk [0,72) pool5 tiles | [72,90) pool9 tiles | [90,92) gmean
__global__ void __launch_bounds__(256) k_c1m(const float* __restrict__ pool5, const float* __restrict__ pool9,
                                             const float* __restrict__ gm,
                                             const float* __restrict__ s2g, const float* __restrict__ s2b,
                                             const float* __restrict__ s3g, const float* __restrict__ s3b,
                                             const float* __restrict__ s4g, const float* __restrict__ s4b,
                                             const float* __restrict__ s4w, const u16* __restrict__ c1k,
                                             float* __restrict__ c2cl, float* __restrict__ c3cl,
                                             float* __restrict__ c4) {
    int blk = blockIdx.x, t = threadIdx.x;
    if (blk >= 90) {   // gmean: 1 px, scalar GEMV
        int b = blk - 90;
        __shared__ float v[64];
        if (t < 64) v[t] = bnrelu(gm[b * 64 + t], s4g[t], s4b[t]);
        __syncthreads();
        if (t < 128) {
            const float* wr = s4w + t * 64;
            float acc = 0.f;
#pragma unroll 16
            for (int c = 0; c < 64; c++) acc += v[c] * wr[c];
            c4[b * 128 + t] = acc;
        }
        return;
    }
    int set, b, pp0, HW;
    const float *in, *g, *bb;
    float* outp;
    if (blk < 72) { set = 0; b = blk / 36; pp0 = (blk % 36) * 16; HW = 576; in = pool5; g = s2g; bb = s2b; outp = c2cl + (size_t)b * 576 * 128; }
    else { int r = blk - 72; set = 1; b = r / 9; pp0 = (r % 9) * 16; HW = 144; in = pool9; g = s3g; bb = s3b; outp = c3cl + (size_t)b * 144 * 128; }
    __shared__ u16 av16[16][72];
#pragma unroll
    for (int i = 0; i < 4; i++) {
        int id = i * 256 + t;
        int c = id >> 4, p = id & 15;
        av16[p][c] = f2bf(bnrelu(in[(size_t)(b * 64 + c) * HW + pp0 + p], g[c], bb[c]));
    }
    __syncthreads();
    int wv = t >> 6, lane = t & 63, ln = lane & 15, q = lane >> 4;
    f32x4 acc[2] = {};
#pragma unroll
    for (int kt = 0; kt < 2; kt++) {
        s16x8 a = *(const s16x8*)(&av16[ln][kt * 32 + q * 8]);
#pragma unroll
        for (int jn = 0; jn < 2; jn++) {
            int nt = wv * 2 + jn;
            s16x8 bfr = *(const s16x8*)(c1k + (size_t)((((set * 2 + kt) * 4 + q) * 8 + nt) * 16 + ln) * 8);
            acc[jn] = __builtin_amdgcn_mfma_f32_16x16x32_bf16(a, bfr, acc[jn], 0, 0, 0);
        }
    }
#pragma unroll
    for (int jn = 0; jn < 2; jn++) {
        int o = (wv * 2 + jn) * 16 + ln;
#pragma unroll
        for (int r = 0; r < 4; r++)
            outp[(size_t)(pp0 + q * 4 + r) * 128 + o] = acc[jn][r];
    }
}

// ------- cat build: x halo staged in LDS, pool3 computed INLINE, MFMA, bilinear, epilogue -------
// 288 blocks x 512 thr (8 waves); each wave owns ONE n-tile (16 ch).
__global__ void __launch_bounds__(512) k_cat2(
    const float* __restrict__ x, const float* __restrict__ c4,
    const float* __restrict__ s0g, const float* __restrict__ s0b,
    const float* __restrict__ s1g, const float* __restrict__ s1b,
    const float* __restrict__ scg, const float* __restrict__ scb,
    const float* __restrict__ cg, const float* __restrict__ cbb,
    const u16* __restrict__ wcat, const float* __restrict__ c2cl, const float* __restrict__ c3cl,
    u16* __restrict__ catbf, u16* __restrict__ xbf) {
    int blk = blockIdx.x;
    int b = blk / 144;
    int l0 = (blk % 144) * 16;
    int hrow = l0 / cW, w0g = l0 % cW;
    int t = threadIdx.x;
    __shared__ float xst[64][3][19];   // zero-padded halo: rows hrow-1..hrow+1, w w0g-1..w0g+16
    __shared__ float axv[16][68];
    __shared__ float ap3[16][68];
    __shared__ u16 axc[16][66];
    // stage halo (3456 entries)
#pragma unroll
    for (int i = 0; i < 7; i++) {
        int id = i * 512 + t;
        if (id < 3456) {
            int c = id / 54, rem = id % 54, rw = rem / 18, wi = rem % 18;
            int hh = hrow + rw - 1, ww = w0g + wi - 1;
            float v = 0.f;
            if (hh >= 0 && hh < cH && ww >= 0 && ww < cW)
                v = x[(size_t)(b * 64 + c) * cL + hh * cW + ww];
            xst[c][rw][wi] = v;
        }
    }
    __syncthreads();
    // bnrelu'd x + inline 3x3 avgpool (count_include_pad -> zero-pad sum /9)
#pragma unroll
    for (int i = 0; i < 2; i++) {
        int id = i * 512 + t;
        int c = id >> 4, p = id & 15;
        float xv = xst[c][1][p + 1];
        float s9 = 0.f;
#pragma unroll
        for (int rw = 0; rw < 3; rw++)
#pragma unroll
            for (int wi = 0; wi < 3; wi++)
                s9 += xst[c][rw][p + wi];
        axv[p][c] = bnrelu(xv, s0g[c], s0b[c]);
        ap3[p][c] = bnrelu(s9 * (1.f / 9.f), s1g[c], s1b[c]);
        axc[p][c] = f2bf(bnrelu(xv, scg[c], scb[c]));
    }
    __syncthreads();
#pragma unroll
    for (int i = 0; i < 2; i++) {
        int idx = i * 512 + t;
        int pp = idx >> 6, cc = idx & 63;
        xbf[((size_t)b * cL + l0 + pp) * 64 + cc] = axc[pp][cc];
    }
    int wv = t >> 6, lane = t & 63, ln = lane & 15, q = lane >> 4;
    f32x4 ax = {};
    f32x4 ay = {};
#pragma unroll
    for (int kt = 0; kt < 2; kt++) {
        s16x8 a0 = cvt8(&axv[ln][kt * 32 + q * 8]);
        s16x8 a1 = cvt8(&ap3[ln][kt * 32 + q * 8]);
        s16x8 b0 = *(const s16x8*)(wcat + (size_t)((((0 * 2 + kt) * 4 + q) * 8 + wv) * 16 + ln) * 8);
        s16x8 b1 = *(const s16x8*)(wcat + (size_t)((((1 * 2 + kt) * 4 + q) * 8 + wv) * 16 + ln) * 8);
        ax = __builtin_amdgcn_mfma_f32_16x16x32_bf16(a0, b0, ax, 0, 0, 0);
        ay = __builtin_amdgcn_mfma_f32_16x16x32_bf16(a1, b1, ay, 0, 0, 0);
    }
    // bilinear setup (row uniform per block)
    float sy2 = hrow * 0.5f - 0.25f;
    float fy2 = floorf(sy2); int iy2 = (int)fy2; float ay2 = sy2 - fy2;
    int y20 = min(max(iy2, 0), 23), y21 = min(max(iy2 + 1, 0), 23);
    float sy3 = hrow * 0.25f - 0.375f;
    float fy3 = floorf(sy3); int iy3 = (int)fy3; float ay3 = sy3 - fy3;
    int y30 = min(max(iy3, 0), 11), y31 = min(max(iy3 + 1, 0), 11);
    const float* c2b = c2cl + (size_t)b * 576 * 128;
    const float* c3b = c3cl + (size_t)b * 144 * 128;
    int ch = wv * 16 + ln;
    float c4v = c4[b * 128 + ch];
#pragma unroll
    for (int r = 0; r < 4; r++) {
        int pp = q * 4 + r;
        int wq = w0g + pp;
        float sx2 = wq * 0.5f - 0.25f;
        float fx2 = floorf(sx2); int ix2 = (int)fx2; float ax2 = sx2 - fx2;
        int x20 = min(max(ix2, 0), 23), x21 = min(max(ix2 + 1, 0), 23);
        float sx3 = wq * 0.25f - 0.375f;
        float fx3 = floorf(sx3); int ix3 = (int)fx3; float ax3 = sx3 - fx3;
        int x30 = min(max(ix3, 0), 11), x31 = min(max(ix3 + 1, 0), 11);
        float v00 = c2b[(y20 * 24 + x20) * 128 + ch], v01 = c2b[(y20 * 24 + x21) * 128 + ch];
        float v10 = c2b[(y21 * 24 + x20) * 128 + ch], v11 = c2b[(y21 * 24 + x21) * 128 + ch];
        float t0 = v00 + (v01 - v00) * ax2, t1 = v10 + (v11 - v10) * ax2;
        float u2v = t0 + (t1 - t0) * ay2;
        float w00 = c3b[(y30 * 12 + x30) * 128 + ch], w01 = c3b[(y30 * 12 + x31) * 128 + ch];
        float w10 = c3b[(y31 * 12 + x30) * 128 + ch], w11 = c3b[(y31 * 12 + x31) * 128 + ch];
        float s0_ = w00 + (w01 - w00) * ax3, s1_ = w10 + (w11 - w10) * ax3;
        float u3v = s0_ + (s1_ - s0_) * ay3;
        float x0 = ax[r];
        float y1 = ay[r] + x0;
        float y2 = x0 + u2v;
        float y3 = x0 + u3v;
        float y4 = x0 + c4v;
        u16* base = catbf + ((size_t)b * cL + l0 + pp) * 640;
        base[ch]       = f2bf(bnrelu(x0, cg[ch],       cbb[ch]));
        base[128 + ch] = f2bf(bnrelu(y1, cg[128 + ch], cbb[128 + ch]));
        base[256 + ch] = f2bf(bnrelu(y2, cg[256 + ch], cbb[256 + ch]));
        base[384 + ch] = f2bf(bnrelu(y3, cg[384 + ch], cbb[384 + ch]));
        base[512 + ch] = f2bf(bnrelu(y4, cg[512 + ch], cbb[512 + ch]));
    }
}

// ------- FUSED comp 3x3 conv + shortcut + split-K reduce + in_proj MFMA -------
__global__ void __launch_bounds__(512) k_compip(const u16* __restrict__ catbf,
                                                const u16* __restrict__ xbf,
                                                const u16* __restrict__ w8,
                                                const u16* __restrict__ ipk,
                                                float* __restrict__ xc, float* __restrict__ z) {
    int pix0 = blockIdx.x * 16;
    int b = pix0 / cL;
    int t = threadIdx.x;
    int wv = t >> 6, lane = t & 63, ln = lane & 15, q = lane >> 4;
    __shared__ float pl[8][16][68];
    __shared__ u16 pv16[16][72];
    int la = (pix0 + ln) - b * cL;
    int h = la / cW, w = la % cW;
    f32x4 acc[4] = {};
    int ks0 = wv * 23;
    int kcnt = (wv == 7) ? 21 : 23;
    for (int i = 0; i < kcnt; i++) {
        int ks = ks0 + i;
        s16x8 av;
        if (ks < 180) {
            int s = ks / 20;
            int cc = ks - s * 20;
            int s3 = s / 3;
            int kh = s3 - 1, kw = s - s3 * 3 - 1;
            int hh = h + kh, ww = w + kw;
            bool ok = (hh >= 0) && (hh < cH) && (ww >= 0) && (ww < cW);
            const u16* ap = catbf + (((size_t)b * cL + hh * cW + ww) * 640 + cc * 32 + q * 8);
            if (ok) av = *(const s16x8*)ap;
            else av = s16x8{0, 0, 0, 0, 0, 0, 0, 0};
        } else {
            int cc = ks - 180;
            av = *(const s16x8*)(xbf + (size_t)(pix0 + ln) * 64 + cc * 32 + q * 8);
        }
        const u16* wrow = w8 + ((size_t)ks * 4 + q) * 512;
#pragma unroll
        for (int j = 0; j < 4; j++) {
            s16x8 bv = *(const s16x8*)(wrow + (size_t)(j * 16 + ln) * 8);
            acc[j] = __builtin_amdgcn_mfma_f32_16x16x32_bf16(av, bv, acc[j], 0, 0, 0);
        }
    }
#pragma unroll
    for (int j = 0; j < 4; j++)
#pragma unroll
        for (int r = 0; r < 4; r++)
            pl[wv][q * 4 + r][j * 16 + ln] = acc[j][r];
    __syncthreads();
#pragma unroll
    for (int e = 0; e < 2; e++) {
        int id = e * 512 + t;
        int p = id >> 6, c = id & 63;
        float s = 0.f;
#pragma unroll
        for (int w2 = 0; w2 < 8; w2++) s += pl[w2][p][c];
        pv16[p][c] = f2bf(s);
    }
    __syncthreads();
    f32x4 a2[2] = {};
#pragma unroll
    for (int kt = 0; kt < 2; kt++) {
        s16x8 a = *(const s16x8*)(&pv16[ln][kt * 32 + q * 8]);
#pragma unroll
        for (int jn = 0; jn < 2; jn++) {
            int nt = wv * 2 + jn;
            s16x8 bfr = *(const s16x8*)(ipk + (size_t)(((kt * 4 + q) * 16 + nt) * 16 + ln) * 8);
            a2[jn] = __builtin_amdgcn_mfma_f32_16x16x32_bf16(a, bfr, a2[jn], 0, 0, 0);
        }
    }
#pragma unroll
    for (int jn = 0; jn < 2; jn++) {
        int o = (wv * 2 + jn) * 16 + ln;
#pragma unroll
        for (int r = 0; r < 4; r++) {
            int p = q * 4 + r;
            if (o < 128) xc[((size_t)pix0 + p) * 128 + o] = a2[jn][r];
            else         z[((size_t)pix0 + p) * 128 + (o - 128)] = a2[jn][r];
        }
    }
}

// ------- FUSED depthwise 3x3 + silu + x_dbl MFMA + softplus (k_dw merged in) -------
// 288 blocks x 1024 thr. Halo 3x18x128 of xc staged in LDS; dw+silu computed
// inline (writes xca for scans + feeds av for MFMA phase).
__global__ void __launch_bounds__(1024) k_xdbl4(const float* __restrict__ xc, const float* __restrict__ dwk,
                                                const float* __restrict__ dwb,
                                                const u16* __restrict__ xpk,
                                                const float* __restrict__ dtw, const float* __restrict__ dtb,
                                                float* __restrict__ bc, float* __restrict__ delta,
                                                float* __restrict__ xca) {
    int blk = blockIdx.x;
    int b = blk / 144;
    int l0 = (blk % 144) * 16;
    int hrow = l0 / cW, w0 = l0 % cW;
    int t = threadIdx.x;
    __shared__ float hal[3][18][128];
    __shared__ float av[16][132];
    __shared__ float Dt[16][148];
    // stage xc halo: 3*18*128 = 6912 entries, coalesced in d
#pragma unroll
    for (int i = 0; i < 7; i++) {
        int id = i * 1024 + t;
        if (id < 6912) {
            int d = id & 127;
            int rem = id >> 7;           // 0..53
            int wi = rem % 18, rw = rem / 18;
            int hh = hrow + rw - 1, ww = w0 + wi - 1;
            float v = 0.f;
            if (hh >= 0 && hh < cH && ww >= 0 && ww < cW)
                v = xc[((size_t)b * cL + hh * cW + ww) * 128 + d];
            hal[rw][wi][d] = v;
        }
    }
    __syncthreads();
    // depthwise 3x3 + bias + silu for the 16 center px (2 outputs/thread)
#pragma unroll
    for (int i = 0; i < 2; i++) {
        int id = i * 1024 + t;
        int d = id & 127, p = id >> 7;
        float acc = dwb[d];
#pragma unroll
        for (int rw = 0; rw < 3; rw++)
#pragma unroll
            for (int wi = 0; wi < 3; wi++)
                acc += hal[rw][p + wi][d] * dwk[(rw * 3 + wi) * 128 + d];
        float v = silu(acc);
        av[p][d] = v;
        xca[((size_t)b * cL + l0 + p) * 128 + d] = v;
    }
    __syncthreads();
    int wv = t >> 6, lane = t & 63, ln = lane & 15, q = lane >> 4;
    if (wv < 9) {
        int nt = wv;
        f32x4 acc = {};
#pragma unroll
        for (int kt = 0; kt < 4; kt++) {
            s16x8 a = cvt8(&av[ln][kt * 32 + q * 8]);
            s16x8 bfr = *(const s16x8*)(xpk + (size_t)(((kt * 4 + q) * 9 + nt) * 16 + ln) * 8);
            acc = __builtin_amdgcn_mfma_f32_16x16x32_bf16(a, bfr, acc, 0, 0, 0);
        }
#pragma unroll
        for (int r = 0; r < 4; r++)
            Dt[q * 4 + r][nt * 16 + ln] = acc[r];
    }
    __syncthreads();
    // bc out: (bk, p_spatial, 32), coalesced — 2048 elems, 2/thread
#pragma unroll
    for (int i = 0; i < 2; i++) {
        int id = i * 1024 + t;
        int cc = id & 31, kk = (id >> 5) & 3, p = id >> 7;
        bc[((size_t)(b * 4 + kk) * cL + l0 + p) * 32 + cc] = Dt[p][kk * 36 + 4 + cc];
    }
    // delta = softplus(dtb + dts . dtw): per-thread (d,kk) constant, p steps by 2
    {
        int d = t & 127;
        int kk = (t >> 7) & 3;
        int p0 = t >> 9;  // 0 or 1
        const float* wd = dtw + (size_t)(kk * 128 + d) * 4;
        float w0_ = wd[0], w1 = wd[1], w2 = wd[2], w3 = wd[3];
        float bb = dtb[kk * 128 + d];
        float* dout = delta + ((size_t)(b * 4 + kk) * cL + l0) * 128 + d;
#pragma unroll
        for (int i = 0; i < 8; i++) {
            int p = p0 + i * 2;
            float pre = bb + w0_ * Dt[p][kk * 36] + w1 * Dt[p][kk * 36 + 1]
                      + w2 * Dt[p][kk * 36 + 2] + w3 * Dt[p][kk * 36 + 3];
            float dl = pre > 20.f ? pre : __logf(1.f + __expf(pre));
            dout[(size_t)p * 128] = dl;
        }
    }
}

// xs index mapping: offset into the (H*W) plane for direction k at scan pos l
__device__ __forceinline__ int xs_index(int k, int l) {
    int lp = (k & 2) ? (cL - 1 - l) : l;
    if (k & 1) { int w = lp / cH, h = lp % cH; return h * cW + w; }
    return lp;
}

// ------- MERGED scan (pass1 + device barrier + prefix-combine + pass3) -------
// 2048 blocks x 256 thr, LDS 18.7 KB, VGPR<=64 via launch_bounds(256,8):
// exactly co-resident (8 blk/CU x 256 CU), so an atomic arrive-and-spin
// barrier is safe. Counter zeroed per iteration via hipMemsetAsync.
__global__ void __launch_bounds__(256, 8) k_scanM(const float* __restrict__ delta, const float* __restrict__ xca,
                                                  const float* __restrict__ bc, const float* __restrict__ Alogs,
                                                  const float* __restrict__ Dsv,
                                                  float* __restrict__ Pend, float* __restrict__ hend,
                                                  float* __restrict__ y, u32* __restrict__ ctr) {
    int blk = blockIdx.x;
    int c = blk & 31;
    int g = blk >> 5;
    int dgq = g & 7, bk = g >> 3;
    int k = bk & 3, b = bk >> 2;
    int t = threadIdx.x;
    int n = t & 15;
    int dq = t >> 4;
    int d0 = dgq * 16;
    __shared__ int soff[CHL];
    __shared__ float sdl[CHL][16];
    __shared__ float sxv[CHL][16];
    __shared__ float sbc[CHL][32];
    if (t < CHL) soff[t] = xs_index(k, c * CHL + t);
    __syncthreads();
    const float* dp = delta + (size_t)bk * cL * 128 + d0;
    const float* xp = xca + (size_t)b * cL * 128 + d0;
    const float* bcp = bc + (size_t)bk * cL * 32;
#pragma unroll
    for (int e = 0; e < 5; e++) {
        int idx = e * 256 + t;
        if (idx < CHL * 16) {
            int i = idx >> 4, j = idx & 15;
            int off = soff[i];
            sdl[i][j] = dp[(size_t)off * 128 + j];
            sxv[i][j] = xp[(size_t)off * 128 + j];
        }
    }
#pragma unroll
    for (int e = 0; e < 9; e++) {
        int idx = e * 256 + t;
        if (idx < CHL * 32) {
            int i = idx >> 5, j = idx & 31;
            sbc[i][j] = bcp[(size_t)soff[i] * 32 + j];
        }
    }
    __syncthreads();
    float A = -__expf(Alogs[(k * 128 + d0 + dq) * 16 + n]);
    // ---- phase 1: chunk-local (P, h); chunk 31's result is never consumed ----
    if (c != NCH - 1) {
        float P = 1.f, h1 = 0.f;
#pragma unroll 8
        for (int i = 0; i < CHL; i++) {
            float dl = sdl[i][dq];
            float a = __expf(dl * A);
            h1 = a * h1 + dl * sxv[i][dq] * sbc[i][n];
            P *= a;
        }
        Pend[(size_t)blk * 256 + t] = P;
        hend[(size_t)blk * 256 + t] = h1;
    }
    // ---- device barrier (all 2048 blocks co-resident) ----
    __threadfence();
    __syncthreads();
    if (t == 0) {
        __hip_atomic_fetch_add(ctr, 1u, __ATOMIC_ACQ_REL, __HIP_MEMORY_SCOPE_AGENT);
        unsigned spins = 0;
        while (__hip_atomic_load(ctr, __ATOMIC_ACQUIRE, __HIP_MEMORY_SCOPE_AGENT) < SCAN_BLOCKS) {
            __builtin_amdgcn_s_sleep(8);
            if (++spins > (1u << 24)) break;   // bail: wrong-answer beats hang
        }
    }
    __syncthreads();
    __threadfence();
    // ---- phase 2: prefix combine over chunks 0..c-1, then rescan from LDS ----
    float h = 0.f;
    for (int cc = 0; cc < c; cc++) {
        size_t idx = ((size_t)g * NCH + cc) * 256 + t;
        h = Pend[idx] * h + hend[idx];
    }
    float Dsd = Dsv[k * 128 + d0 + dq];
    float* yb = y + (size_t)bk * cL * 128 + d0 + dq;
#pragma unroll 8
    for (int i = 0; i < CHL; i++) {
        float dl = sdl[i][dq];
        float xv = sxv[i][dq];
        float a = __expf(dl * A);
        h = a * h + dl * xv * sbc[i][n];
        float contrib = row_sum16(h * sbc[i][16 + n]);
        if (n == 0) yb[(size_t)soff[i] * 128] = contrib + xv * Dsd;
    }
}

// ------- fused tail: 4-dir sum + LN + gate + out_proj + MLP + residual -------
// 1152 blocks x 256 thr, 4 px per block (4.5 waves/SIMD)
__global__ void __launch_bounds__(256) k_tail(const float* __restrict__ y, const float* __restrict__ z,
                                              const float* __restrict__ lng, const float* __restrict__ lnb,
                                              const float* __restrict__ opw,
                                              const float* __restrict__ f1w, const float* __restrict__ f1b,
                                              const float* __restrict__ f2w, const float* __restrict__ f2b,
                                              float* __restrict__ out) {
    int blk = blockIdx.x;
    int b = blk / 576;
    int l0 = (blk % 576) * 4;
    int t = threadIdx.x;
    __shared__ float v[4][132];
    __shared__ float x1s[4][68];
    __shared__ float h1s[4][132];
    __shared__ float mus[4], rss[4];
    const float* yb = y + (size_t)b * 4 * cL * 128;
#pragma unroll
    for (int i = 0; i < 2; i++) {
        int id = i * 256 + t;
        int d = id & 127, p = id >> 7;
        size_t base = (size_t)(l0 + p) * 128 + d;
        v[p][d] = yb[base] + yb[(size_t)cL * 128 + base] + yb[(size_t)2 * cL * 128 + base] + yb[(size_t)3 * cL * 128 + base];
    }
    __syncthreads();
    if (t < 64) {
        int p = t >> 4, c8 = (t & 15) * 8;
        float s = 0.f;
#pragma unroll
        for (int j = 0; j < 8; j++) s += v[p][c8 + j];
        s = row_sum16(s);
        float mu = s * (1.f / 128.f);
        float s2 = 0.f;
#pragma unroll
        for (int j = 0; j < 8; j++) { float dv = v[p][c8 + j] - mu; s2 += dv * dv; }
        s2 = row_sum16(s2);
        if ((t & 15) == 0) { mus[p] = mu; rss[p] = rsqrtf(s2 * (1.f / 128.f) + cEPS); }
    }
    __syncthreads();
#pragma unroll
    for (int i = 0; i < 2; i++) {
        int id = i * 256 + t;
        int d = id & 127, p = id >> 7;
        float zz = z[((size_t)b * cL + l0 + p) * 128 + d];
        v[p][d] = ((v[p][d] - mus[p]) * rss[p] * lng[d] + lnb[d]) * silu(zz);
    }
    __syncthreads();
    {
        int p = t & 3, o = t >> 2;
        const float* wr = opw + o * 128;
        float acc = 0.f;
#pragma unroll 16
        for (int d2 = 0; d2 < 128; d2++) acc += v[p][d2] * wr[d2];
        x1s[p][o] = acc;
    }
    __syncthreads();
#pragma unroll
    for (int i = 0; i < 2; i++) {
        int id = i * 256 + t;
        int p = id & 3, j = id >> 2;
        const float* wr = f1w + j * 64;
        float acc = f1b[j];
#pragma unroll 16
        for (int c = 0; c < 64; c++) acc += x1s[p][c] * wr[c];
        h1s[p][j] = silu(acc);
    }
    __syncthreads();
    {
        int p = t & 3, o = t >> 2;
        const float* wr = f2w + o * 128;
        float acc = f2b[o];
#pragma unroll 16
        for (int j = 0; j < 128; j++) acc += h1s[p][j] * wr[j];
        out[((size_t)b * 64 + o) * cL + l0 + p] = acc + x1s[p][o];
    }
}

extern "C" void kernel_launch(void* const* d_in, const int* in_sizes, int n_in,
                              void* d_out, int out_size, void* d_ws, size_t ws_size,
                              hipStream_t stream) {
    (void)in_sizes; (void)n_in; (void)out_size; (void)ws_size;
    const float* x    = (const float*)d_in[0];
    const float* s0g  = (const float*)d_in[1];
    const float* s0b  = (const float*)d_in[2];
    const float* s0w  = (const float*)d_in[3];
    const float* s1g  = (const float*)d_in[4];
    const float* s1b  = (const float*)d_in[5];
    const float* s1w  = (const float*)d_in[6];
    const float* s2g  = (const float*)d_in[7];
    const float* s2b  = (const float*)d_in[8];
    const float* s2w  = (const float*)d_in[9];
    const float* s3g  = (const float*)d_in[10];
    const float* s3b  = (const float*)d_in[11];
    const float* s3w  = (const float*)d_in[12];
    const float* s4g  = (const float*)d_in[13];
    const float* s4b  = (const float*)d_in[14];
    const float* s4w  = (const float*)d_in[15];
    const float* cg   = (const float*)d_in[16];
    const float* cbb  = (const float*)d_in[17];
    const float* cw   = (const float*)d_in[18];
    const float* scg  = (const float*)d_in[19];
    const float* scb  = (const float*)d_in[20];
    const float* scw  = (const float*)d_in[21];
    const float* ipw  = (const float*)d_in[22];
    const float* dww  = (const float*)d_in[23];
    const float* dwb  = (const float*)d_in[24];
    const float* xpw  = (const float*)d_in[25];
    const float* dtw  = (const float*)d_in[26];
    const float* dtb  = (const float*)d_in[27];
    const float* Alog = (const float*)d_in[28];
    const float* Dsv  = (const float*)d_in[29];
    const float* lng  = (const float*)d_in[30];
    const float* lnb  = (const float*)d_in[31];
    const float* opw  = (const float*)d_in[32];
    const float* f1w  = (const float*)d_in[33];
    const float* f1b  = (const float*)d_in[34];
    const float* f2w  = (const float*)d_in[35];
    const float* f2b  = (const float*)d_in[36];
    float* out = (float*)d_out;

    float* ws = (float*)d_ws;
    size_t off = 0;
    // --- region A: dead before k_xdbl4; delta overlays [0, 2359296) ---
    float* pool5  = ws + off; off += 73728;    // cB*64*576
    float* pool9  = ws + off; off += 18432;    // cB*64*144
    float* gmean  = ws + off; off += 128;      // cB*64
    float* c2cl   = ws + off; off += 147456;   // cB*576*128 (channel-last)
    float* c3cl   = ws + off; off += 36864;    // cB*144*128
    float* c4     = ws + off; off += 256;      // cB*128
    u16*   catbf  = (u16*)(ws + off); off += 1474560;  // cB*cL*640 u16
    u16*   xbf    = (u16*)(ws + off); off += 147456;   // cB*cL*64 u16
    u16*   w8     = (u16*)(ws + off); off += 186368;   // 64*KTOT u16
    u16*   wcat   = (u16*)(ws + off); off += 8192;     // 2*128*64 u16
    u16*   ipk    = (u16*)(ws + off); off += 8192;     // 256*64 u16
    u16*   c1k    = (u16*)(ws + off); off += 8192;     // 2*128*64 u16 (s2w/s3w pack)
    // pad region A so the delta overlay [0, 2359296) never reaches xc
    if (off < 2359296) off = 2359296;
    // --- xc: written k_compip, read k_xdbl4 (dw halo); hend overlays it later. ---
    float* xc     = ws + off; off += 589824;
    u16*   xpk    = (u16*)(ws + off); off += 9216;     // 144*128 u16; read by k_xdbl4
    float* dwk    = ws + off; off += 1280;     // 9*128 tap-major dw weights
    // --- live buffers ---
    float* xca    = ws + off; off += 589824;   // written k_xdbl4 (dw), read scan
    float* zbuf   = ws + off; off += 589824;   // written k_compip, read k_tail
    float* bcbuf  = ws + off; off += 589824;   // written k_xdbl4, read scan
    float* Pend   = ws + off; off += 524288;   // 2048*256
    u32*   scnt   = (u32*)(ws + off); off += 64;   // scan barrier counter
    float* ybuf   = ws + off; off += 2359296;  // scan out
    off += 294912;                             // pad (layout stability)
    // overlays
    float* delta  = ws + 0;    // (bk, p_spatial, 128), written k_xdbl4
    float* hend   = xc;        // 524288 <= 589824; xc dead after k_xdbl4, hend written k_scanM

    k_pp<<<2213, 256, 0, stream>>>(x, pool5, pool9, gmean,
                                   cw, scw, s0w, s1w, ipw, xpw, dww, s2w, s3w,
                                   w8, wcat, ipk, xpk, dwk, c1k);
    k_c1m<<<92, 256, 0, stream>>>(pool5, pool9, gmean, s2g, s2b, s3g, s3b, s4g, s4b, s4w,
                                  c1k, c2cl, c3cl, c4);
    k_cat2<<<cB * 144, 512, 0, stream>>>(x, c4, s0g, s0b, s1g, s1b, scg, scb, cg, cbb,
                                         wcat, c2cl, c3cl, catbf, xbf);
    k_compip<<<cB * cL / 16, 512, 0, stream>>>(catbf, xbf, w8, ipk, xc, zbuf);
    k_xdbl4<<<cB * 144, 1024, 0, stream>>>(xc, dwk, dwb, xpk, dtw, dtb, bcbuf, delta, xca);
    hipMemsetAsync(scnt, 0, sizeof(u32), stream);
    k_scanM<<<SCAN_BLOCKS, 256, 0, stream>>>(delta, xca, bcbuf, Alog, Dsv, Pend, hend, ybuf, scnt);
    k_tail<<<cB * 576, 256, 0, stream>>>(ybuf, zbuf, lng, lnb, opw, f1w, f1b, f2w, f2b, out);
}

// Round 9
// 255.108 us; speedup vs baseline: 2.3915x; 2.3915x over previous
//
#include <hip/hip_runtime.h>
#include <math.h>

constexpr int cB = 2, cC = 64, cH = 48, cW = 48, cL = 48 * 48;
constexpr int cBR = 128, cDI = 128, cNS = 16, cRK = 4, cK = 4;
constexpr float cEPS = 1e-5f;
constexpr int NCH = 32;          // scan chunks
constexpr int CHL = cL / NCH;    // 72 positions per chunk
constexpr int KTOT = 5824;       // 9*640 conv + 64 shortcut

typedef unsigned short u16;
typedef unsigned int u32;
typedef short s16x8 __attribute__((ext_vector_type(8)));
typedef float f32x4 __attribute__((ext_vector_type(4)));

__device__ __forceinline__ float bnrelu(float v, float g, float b) {
    float y = v * (g * rsqrtf(1.0f + cEPS)) + b;
    return y > 0.f ? y : 0.f;
}
__device__ __forceinline__ float silu(float v) {
    return v / (1.f + __expf(-v));
}
__device__ __forceinline__ u16 f2bf(float f) {
    u32 u = __float_as_uint(f);
    u = (u + 0x7fffu + ((u >> 16) & 1u)) >> 16;
    return (u16)u;
}
__device__ __forceinline__ s16x8 cvt8(const float* p) {
    s16x8 r;
#pragma unroll
    for (int i = 0; i < 8; i++) r[i] = (short)f2bf(p[i]);
    return r;
}
// sum over each aligned 16-lane row via DPP (full-rate VALU, no DS pipe)
__device__ __forceinline__ float row_sum16(float v) {
    v += __int_as_float(__builtin_amdgcn_update_dpp(0, __float_as_int(v), 0xB1, 0xF, 0xF, true));  // quad xor1
    v += __int_as_float(__builtin_amdgcn_update_dpp(0, __float_as_int(v), 0x4E, 0xF, 0xF, true));  // quad xor2
    v += __int_as_float(__builtin_amdgcn_update_dpp(0, __float_as_int(v), 0x124, 0xF, 0xF, true)); // row_ror:4
    v += __int_as_float(__builtin_amdgcn_update_dpp(0, __float_as_int(v), 0x128, 0xF, 0xF, true)); // row_ror:8
    return v;
}

// ------- MERGED pools + weight prep + dwk repack + c1k pack (one launch) -------
// blk: [0,288) pool5 | [288,360) pool9 | [360,488) gmean | [488,1944) w8
//      [1944,2008) wcat | [2008,2072) ipk | [2072,2144) xpk | [2144,2149) dwk | [2149,2213) c1k
__global__ void __launch_bounds__(256) k_pp(const float* __restrict__ x,
                                            float* __restrict__ pool5, float* __restrict__ pool9,
                                            float* __restrict__ gmean,
                                            const float* __restrict__ cw, const float* __restrict__ scw,
                                            const float* __restrict__ s0w, const float* __restrict__ s1w,
                                            const float* __restrict__ ipw, const float* __restrict__ xpw,
                                            const float* __restrict__ dww,
                                            const float* __restrict__ s2w, const float* __restrict__ s3w,
                                            u16* __restrict__ w8, u16* __restrict__ wcat,
                                            u16* __restrict__ ipk, u16* __restrict__ xpk,
                                            float* __restrict__ dwk, u16* __restrict__ c1k) {
    __shared__ float sm[4];
    int blk = blockIdx.x;
    int t = threadIdx.x;
    if (blk < 288) {
        int idx = blk * 256 + t;   // 5x5 s2 p2 -> 24x24
        int w = idx % 24, h = (idx / 24) % 24, bc = idx / 576;
        const float* p = x + bc * cL;
        float s = 0.f;
        for (int kh = 0; kh < 5; kh++) {
            int hh = h * 2 - 2 + kh; if (hh < 0 || hh >= cH) continue;
            for (int kw = 0; kw < 5; kw++) {
                int ww = w * 2 - 2 + kw; if (ww < 0 || ww >= cW) continue;
                s += p[hh * cW + ww];
            }
        }
        pool5[idx] = s * (1.f / 25.f);
    } else if (blk < 360) {
        int idx = (blk - 288) * 256 + t;   // 9x9 s4 p4 -> 12x12
        int w = idx % 12, h = (idx / 12) % 12, bc = idx / 144;
        const float* p = x + bc * cL;
        float s = 0.f;
        for (int kh = 0; kh < 9; kh++) {
            int hh = h * 4 - 4 + kh; if (hh < 0 || hh >= cH) continue;
            for (int kw = 0; kw < 9; kw++) {
                int ww = w * 4 - 4 + kw; if (ww < 0 || ww >= cW) continue;
                s += p[hh * cW + ww];
            }
        }
        pool9[idx] = s * (1.f / 81.f);
    } else if (blk < 488) {
        int bc = blk - 360;
        const float* p = x + bc * cL;
        float s = 0.f;
        for (int i = t; i < cL; i += 256) s += p[i];
        for (int m = 32; m > 0; m >>= 1) s += __shfl_down(s, m);
        if ((t & 63) == 0) sm[t >> 6] = s;
        __syncthreads();
        if (t == 0) gmean[bc] = (sm[0] + sm[1] + sm[2] + sm[3]) * (1.f / cL);
    } else if (blk < 1944) {
        int idx = (blk - 488) * 256 + t;  // < 64*KTOT exactly
        int o = idx / KTOT, kx = idx % KTOT;
        float v;
        if (kx < 5760) { int tap = kx / 640, ch = kx % 640; v = cw[(o * 640 + ch) * 9 + tap]; }
        else v = scw[o * 64 + (kx - 5760)];
        w8[(((size_t)(kx >> 3) * 64) + o) * 8 + (kx & 7)] = f2bf(v);
    } else if (blk < 2008) {
        int idx = (blk - 1944) * 256 + t;
        int g = idx >> 13, r = idx & 8191;
        int o = r >> 6, c = r & 63;
        float v = (g ? s1w : s0w)[r];
        int kt = c >> 5, q = (c >> 3) & 3, j = c & 7, nt = o >> 4, ln = o & 15;
        wcat[(size_t)((((g * 2 + kt) * 4 + q) * 8 + nt) * 16 + ln) * 8 + j] = f2bf(v);
    } else if (blk < 2072) {
        int idx = (blk - 2008) * 256 + t;
        int o = idx >> 6, c = idx & 63;
        int kt = c >> 5, q = (c >> 3) & 3, j = c & 7, nt = o >> 4, ln = o & 15;
        ipk[(size_t)(((kt * 4 + q) * 16 + nt) * 16 + ln) * 8 + j] = f2bf(ipw[idx]);
    } else if (blk < 2144) {
        int idx = (blk - 2072) * 256 + t;
        int o = idx >> 7, d = idx & 127;
        int kt = d >> 5, q = (d >> 3) & 3, j = d & 7, nt = o >> 4, ln = o & 15;
        xpk[(size_t)(((kt * 4 + q) * 9 + nt) * 16 + ln) * 8 + j] = f2bf(xpw[idx]);
    } else if (blk < 2149) {
        int idx = (blk - 2144) * 256 + t;   // dwk[tap][ch] = dww[ch*9+tap], 1152 elems
        if (idx < 1152) {
            int tap = idx >> 7, ch = idx & 127;
            dwk[idx] = dww[ch * 9 + tap];
        }
    } else {
        int idx = (blk - 2149) * 256 + t;   // pack s2w/s3w for MFMA (like wcat)
        int g = idx >> 13, r = idx & 8191;
        int o = r >> 6, c = r & 63;
        float v = (g ? s3w : s2w)[r];
        int kt = c >> 5, q = (c >> 3) & 3, j = c & 7, nt = o >> 4, ln = o & 15;
        c1k[(size_t)((((g * 2 + kt) * 4 + q) * 8 + nt) * 16 + ln) * 8 + j] = f2bf(v);
    }
}

// ------- bn_relu + 1x1 conv (64->128) via MFMA tiles; gmean scalar path -------
// blk [0,72) pool5 tiles | [72,90) pool9 tiles | [90,92) gmean
__global__ void __launch_bounds__(256) k_c1m(const float* __restrict__ pool5, const float* __restrict__ pool9,
                                             const float* __restrict__ gm,
                                             const float* __restrict__ s2g, const float* __restrict__ s2b,
                                             const float* __restrict__ s3g, const float* __restrict__ s3b,
                                             const float* __restrict__ s4g, const float* __restrict__ s4b,
                                             const float* __restrict__ s4w, const u16* __restrict__ c1k,
                                             float* __restrict__ c2cl, float* __restrict__ c3cl,
                                             float* __restrict__ c4) {
    int blk = blockIdx.x, t = threadIdx.x;
    if (blk >= 90) {   // gmean: 1 px, scalar GEMV
        int b = blk - 90;
        __shared__ float v[64];
        if (t < 64) v[t] = bnrelu(gm[b * 64 + t], s4g[t], s4b[t]);
        __syncthreads();
        if (t < 128) {
            const float* wr = s4w + t * 64;
            float acc = 0.f;
#pragma unroll 16
            for (int c = 0; c < 64; c++) acc += v[c] * wr[c];
            c4[b * 128 + t] = acc;
        }
        return;
    }
    int set, b, pp0, HW;
    const float *in, *g, *bb;
    float* outp;
    if (blk < 72) { set = 0; b = blk / 36; pp0 = (blk % 36) * 16; HW = 576; in = pool5; g = s2g; bb = s2b; outp = c2cl + (size_t)b * 576 * 128; }
    else { int r = blk - 72; set = 1; b = r / 9; pp0 = (r % 9) * 16; HW = 144; in = pool9; g = s3g; bb = s3b; outp = c3cl + (size_t)b * 144 * 128; }
    __shared__ u16 av16[16][72];
#pragma unroll
    for (int i = 0; i < 4; i++) {
        int id = i * 256 + t;
        int c = id >> 4, p = id & 15;
        av16[p][c] = f2bf(bnrelu(in[(size_t)(b * 64 + c) * HW + pp0 + p], g[c], bb[c]));
    }
    __syncthreads();
    int wv = t >> 6, lane = t & 63, ln = lane & 15, q = lane >> 4;
    f32x4 acc[2] = {};
#pragma unroll
    for (int kt = 0; kt < 2; kt++) {
        s16x8 a = *(const s16x8*)(&av16[ln][kt * 32 + q * 8]);
#pragma unroll
        for (int jn = 0; jn < 2; jn++) {
            int nt = wv * 2 + jn;
            s16x8 bfr = *(const s16x8*)(c1k + (size_t)((((set * 2 + kt) * 4 + q) * 8 + nt) * 16 + ln) * 8);
            acc[jn] = __builtin_amdgcn_mfma_f32_16x16x32_bf16(a, bfr, acc[jn], 0, 0, 0);
        }
    }
#pragma unroll
    for (int jn = 0; jn < 2; jn++) {
        int o = (wv * 2 + jn) * 16 + ln;
#pragma unroll
        for (int r = 0; r < 4; r++)
            outp[(size_t)(pp0 + q * 4 + r) * 128 + o] = acc[jn][r];
    }
}

// ------- cat build: x halo staged in LDS, pool3 computed INLINE, MFMA, bilinear, epilogue -------
// 288 blocks x 512 thr (8 waves); each wave owns ONE n-tile (16 ch).
__global__ void __launch_bounds__(512) k_cat2(
    const float* __restrict__ x, const float* __restrict__ c4,
    const float* __restrict__ s0g, const float* __restrict__ s0b,
    const float* __restrict__ s1g, const float* __restrict__ s1b,
    const float* __restrict__ scg, const float* __restrict__ scb,
    const float* __restrict__ cg, const float* __restrict__ cbb,
    const u16* __restrict__ wcat, const float* __restrict__ c2cl, const float* __restrict__ c3cl,
    u16* __restrict__ catbf, u16* __restrict__ xbf) {
    int blk = blockIdx.x;
    int b = blk / 144;
    int l0 = (blk % 144) * 16;
    int hrow = l0 / cW, w0g = l0 % cW;
    int t = threadIdx.x;
    __shared__ float xst[64][3][19];   // zero-padded halo: rows hrow-1..hrow+1, w w0g-1..w0g+16
    __shared__ float axv[16][68];
    __shared__ float ap3[16][68];
    __shared__ u16 axc[16][66];
    // stage halo (3456 entries)
#pragma unroll
    for (int i = 0; i < 7; i++) {
        int id = i * 512 + t;
        if (id < 3456) {
            int c = id / 54, rem = id % 54, rw = rem / 18, wi = rem % 18;
            int hh = hrow + rw - 1, ww = w0g + wi - 1;
            float v = 0.f;
            if (hh >= 0 && hh < cH && ww >= 0 && ww < cW)
                v = x[(size_t)(b * 64 + c) * cL + hh * cW + ww];
            xst[c][rw][wi] = v;
        }
    }
    __syncthreads();
    // bnrelu'd x + inline 3x3 avgpool (count_include_pad -> zero-pad sum /9)
#pragma unroll
    for (int i = 0; i < 2; i++) {
        int id = i * 512 + t;
        int c = id >> 4, p = id & 15;
        float xv = xst[c][1][p + 1];
        float s9 = 0.f;
#pragma unroll
        for (int rw = 0; rw < 3; rw++)
#pragma unroll
            for (int wi = 0; wi < 3; wi++)
                s9 += xst[c][rw][p + wi];
        axv[p][c] = bnrelu(xv, s0g[c], s0b[c]);
        ap3[p][c] = bnrelu(s9 * (1.f / 9.f), s1g[c], s1b[c]);
        axc[p][c] = f2bf(bnrelu(xv, scg[c], scb[c]));
    }
    __syncthreads();
#pragma unroll
    for (int i = 0; i < 2; i++) {
        int idx = i * 512 + t;
        int pp = idx >> 6, cc = idx & 63;
        xbf[((size_t)b * cL + l0 + pp) * 64 + cc] = axc[pp][cc];
    }
    int wv = t >> 6, lane = t & 63, ln = lane & 15, q = lane >> 4;
    f32x4 ax = {};
    f32x4 ay = {};
#pragma unroll
    for (int kt = 0; kt < 2; kt++) {
        s16x8 a0 = cvt8(&axv[ln][kt * 32 + q * 8]);
        s16x8 a1 = cvt8(&ap3[ln][kt * 32 + q * 8]);
        s16x8 b0 = *(const s16x8*)(wcat + (size_t)((((0 * 2 + kt) * 4 + q) * 8 + wv) * 16 + ln) * 8);
        s16x8 b1 = *(const s16x8*)(wcat + (size_t)((((1 * 2 + kt) * 4 + q) * 8 + wv) * 16 + ln) * 8);
        ax = __builtin_amdgcn_mfma_f32_16x16x32_bf16(a0, b0, ax, 0, 0, 0);
        ay = __builtin_amdgcn_mfma_f32_16x16x32_bf16(a1, b1, ay, 0, 0, 0);
    }
    // bilinear setup (row uniform per block)
    float sy2 = hrow * 0.5f - 0.25f;
    float fy2 = floorf(sy2); int iy2 = (int)fy2; float ay2 = sy2 - fy2;
    int y20 = min(max(iy2, 0), 23), y21 = min(max(iy2 + 1, 0), 23);
    float sy3 = hrow * 0.25f - 0.375f;
    float fy3 = floorf(sy3); int iy3 = (int)fy3; float ay3 = sy3 - fy3;
    int y30 = min(max(iy3, 0), 11), y31 = min(max(iy3 + 1, 0), 11);
    const float* c2b = c2cl + (size_t)b * 576 * 128;
    const float* c3b = c3cl + (size_t)b * 144 * 128;
    int ch = wv * 16 + ln;
    float c4v = c4[b * 128 + ch];
#pragma unroll
    for (int r = 0; r < 4; r++) {
        int pp = q * 4 + r;
        int wq = w0g + pp;
        float sx2 = wq * 0.5f - 0.25f;
        float fx2 = floorf(sx2); int ix2 = (int)fx2; float ax2 = sx2 - fx2;
        int x20 = min(max(ix2, 0), 23), x21 = min(max(ix2 + 1, 0), 23);
        float sx3 = wq * 0.25f - 0.375f;
        float fx3 = floorf(sx3); int ix3 = (int)fx3; float ax3 = sx3 - fx3;
        int x30 = min(max(ix3, 0), 11), x31 = min(max(ix3 + 1, 0), 11);
        float v00 = c2b[(y20 * 24 + x20) * 128 + ch], v01 = c2b[(y20 * 24 + x21) * 128 + ch];
        float v10 = c2b[(y21 * 24 + x20) * 128 + ch], v11 = c2b[(y21 * 24 + x21) * 128 + ch];
        float t0 = v00 + (v01 - v00) * ax2, t1 = v10 + (v11 - v10) * ax2;
        float u2v = t0 + (t1 - t0) * ay2;
        float w00 = c3b[(y30 * 12 + x30) * 128 + ch], w01 = c3b[(y30 * 12 + x31) * 128 + ch];
        float w10 = c3b[(y31 * 12 + x30) * 128 + ch], w11 = c3b[(y31 * 12 + x31) * 128 + ch];
        float s0_ = w00 + (w01 - w00) * ax3, s1_ = w10 + (w11 - w10) * ax3;
        float u3v = s0_ + (s1_ - s0_) * ay3;
        float x0 = ax[r];
        float y1 = ay[r] + x0;
        float y2 = x0 + u2v;
        float y3 = x0 + u3v;
        float y4 = x0 + c4v;
        u16* base = catbf + ((size_t)b * cL + l0 + pp) * 640;
        base[ch]       = f2bf(bnrelu(x0, cg[ch],       cbb[ch]));
        base[128 + ch] = f2bf(bnrelu(y1, cg[128 + ch], cbb[128 + ch]));
        base[256 + ch] = f2bf(bnrelu(y2, cg[256 + ch], cbb[256 + ch]));
        base[384 + ch] = f2bf(bnrelu(y3, cg[384 + ch], cbb[384 + ch]));
        base[512 + ch] = f2bf(bnrelu(y4, cg[512 + ch], cbb[512 + ch]));
    }
}

// ------- FUSED comp 3x3 conv + shortcut + split-K reduce + in_proj MFMA -------
__global__ void __launch_bounds__(512) k_compip(const u16* __restrict__ catbf,
                                                const u16* __restrict__ xbf,
                                                const u16* __restrict__ w8,
                                                const u16* __restrict__ ipk,
                                                float* __restrict__ xc, float* __restrict__ z) {
    int pix0 = blockIdx.x * 16;
    int b = pix0 / cL;
    int t = threadIdx.x;
    int wv = t >> 6, lane = t & 63, ln = lane & 15, q = lane >> 4;
    __shared__ float pl[8][16][68];
    __shared__ u16 pv16[16][72];
    int la = (pix0 + ln) - b * cL;
    int h = la / cW, w = la % cW;
    f32x4 acc[4] = {};
    int ks0 = wv * 23;
    int kcnt = (wv == 7) ? 21 : 23;
    for (int i = 0; i < kcnt; i++) {
        int ks = ks0 + i;
        s16x8 av;
        if (ks < 180) {
            int s = ks / 20;
            int cc = ks - s * 20;
            int s3 = s / 3;
            int kh = s3 - 1, kw = s - s3 * 3 - 1;
            int hh = h + kh, ww = w + kw;
            bool ok = (hh >= 0) && (hh < cH) && (ww >= 0) && (ww < cW);
            const u16* ap = catbf + (((size_t)b * cL + hh * cW + ww) * 640 + cc * 32 + q * 8);
            if (ok) av = *(const s16x8*)ap;
            else av = s16x8{0, 0, 0, 0, 0, 0, 0, 0};
        } else {
            int cc = ks - 180;
            av = *(const s16x8*)(xbf + (size_t)(pix0 + ln) * 64 + cc * 32 + q * 8);
        }
        const u16* wrow = w8 + ((size_t)ks * 4 + q) * 512;
#pragma unroll
        for (int j = 0; j < 4; j++) {
            s16x8 bv = *(const s16x8*)(wrow + (size_t)(j * 16 + ln) * 8);
            acc[j] = __builtin_amdgcn_mfma_f32_16x16x32_bf16(av, bv, acc[j], 0, 0, 0);
        }
    }
#pragma unroll
    for (int j = 0; j < 4; j++)
#pragma unroll
        for (int r = 0; r < 4; r++)
            pl[wv][q * 4 + r][j * 16 + ln] = acc[j][r];
    __syncthreads();
#pragma unroll
    for (int e = 0; e < 2; e++) {
        int id = e * 512 + t;
        int p = id >> 6, c = id & 63;
        float s = 0.f;
#pragma unroll
        for (int w2 = 0; w2 < 8; w2++) s += pl[w2][p][c];
        pv16[p][c] = f2bf(s);
    }
    __syncthreads();
    f32x4 a2[2] = {};
#pragma unroll
    for (int kt = 0; kt < 2; kt++) {
        s16x8 a = *(const s16x8*)(&pv16[ln][kt * 32 + q * 8]);
#pragma unroll
        for (int jn = 0; jn < 2; jn++) {
            int nt = wv * 2 + jn;
            s16x8 bfr = *(const s16x8*)(ipk + (size_t)(((kt * 4 + q) * 16 + nt) * 16 + ln) * 8);
            a2[jn] = __builtin_amdgcn_mfma_f32_16x16x32_bf16(a, bfr, a2[jn], 0, 0, 0);
        }
    }
#pragma unroll
    for (int jn = 0; jn < 2; jn++) {
        int o = (wv * 2 + jn) * 16 + ln;
#pragma unroll
        for (int r = 0; r < 4; r++) {
            int p = q * 4 + r;
            if (o < 128) xc[((size_t)pix0 + p) * 128 + o] = a2[jn][r];
            else         z[((size_t)pix0 + p) * 128 + (o - 128)] = a2[jn][r];
        }
    }
}

// ------- FUSED depthwise 3x3 + silu + x_dbl MFMA + softplus (k_dw merged in) -------
// 288 blocks x 1024 thr. Halo 3x18x128 of xc staged in LDS; dw+silu computed
// inline (writes xca for scans + feeds av for MFMA phase).
__global__ void __launch_bounds__(1024) k_xdbl4(const float* __restrict__ xc, const float* __restrict__ dwk,
                                                const float* __restrict__ dwb,
                                                const u16* __restrict__ xpk,
                                                const float* __restrict__ dtw, const float* __restrict__ dtb,
                                                float* __restrict__ bc, float* __restrict__ delta,
                                                float* __restrict__ xca) {
    int blk = blockIdx.x;
    int b = blk / 144;
    int l0 = (blk % 144) * 16;
    int hrow = l0 / cW, w0 = l0 % cW;
    int t = threadIdx.x;
    __shared__ float hal[3][18][128];
    __shared__ float av[16][132];
    __shared__ float Dt[16][148];
    // stage xc halo: 3*18*128 = 6912 entries, coalesced in d
#pragma unroll
    for (int i = 0; i < 7; i++) {
        int id = i * 1024 + t;
        if (id < 6912) {
            int d = id & 127;
            int rem = id >> 7;           // 0..53
            int wi = rem % 18, rw = rem / 18;
            int hh = hrow + rw - 1, ww = w0 + wi - 1;
            float v = 0.f;
            if (hh >= 0 && hh < cH && ww >= 0 && ww < cW)
                v = xc[((size_t)b * cL + hh * cW + ww) * 128 + d];
            hal[rw][wi][d] = v;
        }
    }
    __syncthreads();
    // depthwise 3x3 + bias + silu for the 16 center px (2 outputs/thread)
#pragma unroll
    for (int i = 0; i < 2; i++) {
        int id = i * 1024 + t;
        int d = id & 127, p = id >> 7;
        float acc = dwb[d];
#pragma unroll
        for (int rw = 0; rw < 3; rw++)
#pragma unroll
            for (int wi = 0; wi < 3; wi++)
                acc += hal[rw][p + wi][d] * dwk[(rw * 3 + wi) * 128 + d];
        float v = silu(acc);
        av[p][d] = v;
        xca[((size_t)b * cL + l0 + p) * 128 + d] = v;
    }
    __syncthreads();
    int wv = t >> 6, lane = t & 63, ln = lane & 15, q = lane >> 4;
    if (wv < 9) {
        int nt = wv;
        f32x4 acc = {};
#pragma unroll
        for (int kt = 0; kt < 4; kt++) {
            s16x8 a = cvt8(&av[ln][kt * 32 + q * 8]);
            s16x8 bfr = *(const s16x8*)(xpk + (size_t)(((kt * 4 + q) * 9 + nt) * 16 + ln) * 8);
            acc = __builtin_amdgcn_mfma_f32_16x16x32_bf16(a, bfr, acc, 0, 0, 0);
        }
#pragma unroll
        for (int r = 0; r < 4; r++)
            Dt[q * 4 + r][nt * 16 + ln] = acc[r];
    }
    __syncthreads();
    // bc out: (bk, p_spatial, 32), coalesced — 2048 elems, 2/thread
#pragma unroll
    for (int i = 0; i < 2; i++) {
        int id = i * 1024 + t;
        int cc = id & 31, kk = (id >> 5) & 3, p = id >> 7;
        bc[((size_t)(b * 4 + kk) * cL + l0 + p) * 32 + cc] = Dt[p][kk * 36 + 4 + cc];
    }
    // delta = softplus(dtb + dts . dtw): per-thread (d,kk) constant, p steps by 2
    {
        int d = t & 127;
        int kk = (t >> 7) & 3;
        int p0 = t >> 9;  // 0 or 1
        const float* wd = dtw + (size_t)(kk * 128 + d) * 4;
        float w0_ = wd[0], w1 = wd[1], w2 = wd[2], w3 = wd[3];
        float bb = dtb[kk * 128 + d];
        float* dout = delta + ((size_t)(b * 4 + kk) * cL + l0) * 128 + d;
#pragma unroll
        for (int i = 0; i < 8; i++) {
            int p = p0 + i * 2;
            float pre = bb + w0_ * Dt[p][kk * 36] + w1 * Dt[p][kk * 36 + 1]
                      + w2 * Dt[p][kk * 36 + 2] + w3 * Dt[p][kk * 36 + 3];
            float dl = pre > 20.f ? pre : __logf(1.f + __expf(pre));
            dout[(size_t)p * 128] = dl;
        }
    }
}

// xs index mapping: offset into the (H*W) plane for direction k at scan pos l
__device__ __forceinline__ int xs_index(int k, int l) {
    int lp = (k & 2) ? (cL - 1 - l) : l;
    if (k & 1) { int w = lp / cH, h = lp % cH; return h * cW + w; }
    return lp;
}

// ------- scan pass 1: LDS-staged chunk (closed-form offsets), then pure-LDS recurrence -------
__global__ void __launch_bounds__(256) k_scan1(const float* __restrict__ delta, const float* __restrict__ xca,
                                               const float* __restrict__ bc, const float* __restrict__ Alogs,
                                               float* __restrict__ Pend, float* __restrict__ hend) {
    int blk = blockIdx.x;            // ((bk*8+dgq)*NCH + c)
    int c = blk & 31;
    if (c == NCH - 1) return;        // last chunk's P/h never consumed
    int g = blk >> 5;
    int dgq = g & 7, bk = g >> 3;
    int k = bk & 3, b = bk >> 2;
    int t = threadIdx.x;
    int n = t & 15;
    int dq = t >> 4;                 // 0..15
    int d0 = dgq * 16;
    __shared__ int soff[CHL];
    __shared__ float sdl[CHL][16];
    __shared__ float sxv[CHL][16];
    __shared__ float sbp[CHL][16];
    if (t < CHL) soff[t] = xs_index(k, c * CHL + t);
    __syncthreads();
    const float* dp = delta + (size_t)bk * cL * 128 + d0;
    const float* xp = xca + (size_t)b * cL * 128 + d0;
    const float* bcp = bc + (size_t)bk * cL * 32;
#pragma unroll
    for (int e = 0; e < 5; e++) {
        int idx = e * 256 + t;
        if (idx < CHL * 16) {
            int i = idx >> 4, j = idx & 15;
            int off = soff[i];
            sdl[i][j] = dp[(size_t)off * 128 + j];
            sxv[i][j] = xp[(size_t)off * 128 + j];
            sbp[i][j] = bcp[(size_t)off * 32 + j];
        }
    }
    __syncthreads();
    float A = -__expf(Alogs[(k * 128 + d0 + dq) * 16 + n]);
    float P = 1.f, h = 0.f;
#pragma unroll 8
    for (int i = 0; i < CHL; i++) {
        float dl = sdl[i][dq];
        float a = __expf(dl * A);
        h = a * h + dl * sxv[i][dq] * sbp[i][n];
        P *= a;
    }
    Pend[(size_t)blk * 256 + t] = P;
    hend[(size_t)blk * 256 + t] = h;
}

// ------- scan pass 3: prefix combine + LDS-staged chunk re-scan -------
__global__ void __launch_bounds__(256) k_scan3(const float* __restrict__ delta, const float* __restrict__ xca,
                                               const float* __restrict__ bc, const float* __restrict__ Alogs,
                                               const float* __restrict__ Dsv,
                                               const float* __restrict__ Pend, const float* __restrict__ hend,
                                               float* __restrict__ y) {
    int blk = blockIdx.x;
    int c = blk & 31;
    int g = blk >> 5;
    int dgq = g & 7, bk = g >> 3;
    int k = bk & 3, b = bk >> 2;
    int t = threadIdx.x;
    int n = t & 15;
    int dq = t >> 4;
    int d0 = dgq * 16;
    __shared__ int soff[CHL];
    __shared__ float sdl[CHL][16];
    __shared__ float sxv[CHL][16];
    __shared__ float sbc[CHL][32];
    if (t < CHL) soff[t] = xs_index(k, c * CHL + t);
    __syncthreads();
    const float* dp = delta + (size_t)bk * cL * 128 + d0;
    const float* xp = xca + (size_t)b * cL * 128 + d0;
    const float* bcp = bc + (size_t)bk * cL * 32;
#pragma unroll
    for (int e = 0; e < 5; e++) {
        int idx = e * 256 + t;
        if (idx < CHL * 16) {
            int i = idx >> 4, j = idx & 15;
            int off = soff[i];
            sdl[i][j] = dp[(size_t)off * 128 + j];
            sxv[i][j] = xp[(size_t)off * 128 + j];
        }
    }
#pragma unroll
    for (int e = 0; e < 9; e++) {
        int idx = e * 256 + t;
        if (idx < CHL * 32) {
            int i = idx >> 5, j = idx & 31;
            sbc[i][j] = bcp[(size_t)soff[i] * 32 + j];
        }
    }
    // inline combine: h_in = prefix over chunks 0..c-1 (L2-hot)
    float h = 0.f;
    for (int cc = 0; cc < c; cc++) {
        size_t idx = ((size_t)g * NCH + cc) * 256 + t;
        h = Pend[idx] * h + hend[idx];
    }
    __syncthreads();
    float A = -__expf(Alogs[(k * 128 + d0 + dq) * 16 + n]);
    float Dsd = Dsv[k * 128 + d0 + dq];
    float* yb = y + (size_t)bk * cL * 128 + d0 + dq;
#pragma unroll 8
    for (int i = 0; i < CHL; i++) {
        float dl = sdl[i][dq];
        float xv = sxv[i][dq];
        float a = __expf(dl * A);
        h = a * h + dl * xv * sbc[i][n];
        float contrib = row_sum16(h * sbc[i][16 + n]);
        if (n == 0) yb[(size_t)soff[i] * 128] = contrib + xv * Dsd;
    }
}

// ------- fused tail: 4-dir sum + LN + gate + out_proj + MLP + residual -------
// 1152 blocks x 256 thr, 4 px per block (4.5 waves/SIMD)
__global__ void __launch_bounds__(256) k_tail(const float* __restrict__ y, const float* __restrict__ z,
                                              const float* __restrict__ lng, const float* __restrict__ lnb,
                                              const float* __restrict__ opw,
                                              const float* __restrict__ f1w, const float* __restrict__ f1b,
                                              const float* __restrict__ f2w, const float* __restrict__ f2b,
                                              float* __restrict__ out) {
    int blk = blockIdx.x;
    int b = blk / 576;
    int l0 = (blk % 576) * 4;
    int t = threadIdx.x;
    __shared__ float v[4][132];
    __shared__ float x1s[4][68];
    __shared__ float h1s[4][132];
    __shared__ float mus[4], rss[4];
    const float* yb = y + (size_t)b * 4 * cL * 128;
#pragma unroll
    for (int i = 0; i < 2; i++) {
        int id = i * 256 + t;
        int d = id & 127, p = id >> 7;
        size_t base = (size_t)(l0 + p) * 128 + d;
        v[p][d] = yb[base] + yb[(size_t)cL * 128 + base] + yb[(size_t)2 * cL * 128 + base] + yb[(size_t)3 * cL * 128 + base];
    }
    __syncthreads();
    if (t < 64) {
        int p = t >> 4, c8 = (t & 15) * 8;
        float s = 0.f;
#pragma unroll
        for (int j = 0; j < 8; j++) s += v[p][c8 + j];
        s = row_sum16(s);
        float mu = s * (1.f / 128.f);
        float s2 = 0.f;
#pragma unroll
        for (int j = 0; j < 8; j++) { float dv = v[p][c8 + j] - mu; s2 += dv * dv; }
        s2 = row_sum16(s2);
        if ((t & 15) == 0) { mus[p] = mu; rss[p] = rsqrtf(s2 * (1.f / 128.f) + cEPS); }
    }
    __syncthreads();
#pragma unroll
    for (int i = 0; i < 2; i++) {
        int id = i * 256 + t;
        int d = id & 127, p = id >> 7;
        float zz = z[((size_t)b * cL + l0 + p) * 128 + d];
        v[p][d] = ((v[p][d] - mus[p]) * rss[p] * lng[d] + lnb[d]) * silu(zz);
    }
    __syncthreads();
    {
        int p = t & 3, o = t >> 2;
        const float* wr = opw + o * 128;
        float acc = 0.f;
#pragma unroll 16
        for (int d2 = 0; d2 < 128; d2++) acc += v[p][d2] * wr[d2];
        x1s[p][o] = acc;
    }
    __syncthreads();
#pragma unroll
    for (int i = 0; i < 2; i++) {
        int id = i * 256 + t;
        int p = id & 3, j = id >> 2;
        const float* wr = f1w + j * 64;
        float acc = f1b[j];
#pragma unroll 16
        for (int c = 0; c < 64; c++) acc += x1s[p][c] * wr[c];
        h1s[p][j] = silu(acc);
    }
    __syncthreads();
    {
        int p = t & 3, o = t >> 2;
        const float* wr = f2w + o * 128;
        float acc = f2b[o];
#pragma unroll 16
        for (int j = 0; j < 128; j++) acc += h1s[p][j] * wr[j];
        out[((size_t)b * 64 + o) * cL + l0 + p] = acc + x1s[p][o];
    }
}

extern "C" void kernel_launch(void* const* d_in, const int* in_sizes, int n_in,
                              void* d_out, int out_size, void* d_ws, size_t ws_size,
                              hipStream_t stream) {
    (void)in_sizes; (void)n_in; (void)out_size; (void)ws_size;
    const float* x    = (const float*)d_in[0];
    const float* s0g  = (const float*)d_in[1];
    const float* s0b  = (const float*)d_in[2];
    const float* s0w  = (const float*)d_in[3];
    const float* s1g  = (const float*)d_in[4];
    const float* s1b  = (const float*)d_in[5];
    const float* s1w  = (const float*)d_in[6];
    const float* s2g  = (const float*)d_in[7];
    const float* s2b  = (const float*)d_in[8];
    const float* s2w  = (const float*)d_in[9];
    const float* s3g  = (const float*)d_in[10];
    const float* s3b  = (const float*)d_in[11];
    const float* s3w  = (const float*)d_in[12];
    const float* s4g  = (const float*)d_in[13];
    const float* s4b  = (const float*)d_in[14];
    const float* s4w  = (const float*)d_in[15];
    const float* cg   = (const float*)d_in[16];
    const float* cbb  = (const float*)d_in[17];
    const float* cw   = (const float*)d_in[18];
    const float* scg  = (const float*)d_in[19];
    const float* scb  = (const float*)d_in[20];
    const float* scw  = (const float*)d_in[21];
    const float* ipw  = (const float*)d_in[22];
    const float* dww  = (const float*)d_in[23];
    const float* dwb  = (const float*)d_in[24];
    const float* xpw  = (const float*)d_in[25];
    const float* dtw  = (const float*)d_in[26];
    const float* dtb  = (const float*)d_in[27];
    const float* Alog = (const float*)d_in[28];
    const float* Dsv  = (const float*)d_in[29];
    const float* lng  = (const float*)d_in[30];
    const float* lnb  = (const float*)d_in[31];
    const float* opw  = (const float*)d_in[32];
    const float* f1w  = (const float*)d_in[33];
    const float* f1b  = (const float*)d_in[34];
    const float* f2w  = (const float*)d_in[35];
    const float* f2b  = (const float*)d_in[36];
    float* out = (float*)d_out;

    float* ws = (float*)d_ws;
    size_t off = 0;
    // --- region A: dead before k_xdbl4; delta overlays [0, 2359296) ---
    float* pool5  = ws + off; off += 73728;    // cB*64*576
    float* pool9  = ws + off; off += 18432;    // cB*64*144
    float* gmean  = ws + off; off += 128;      // cB*64
    float* c2cl   = ws + off; off += 147456;   // cB*576*128 (channel-last)
    float* c3cl   = ws + off; off += 36864;    // cB*144*128
    float* c4     = ws + off; off += 256;      // cB*128
    u16*   catbf  = (u16*)(ws + off); off += 1474560;  // cB*cL*640 u16
    u16*   xbf    = (u16*)(ws + off); off += 147456;   // cB*cL*64 u16
    u16*   w8     = (u16*)(ws + off); off += 186368;   // 64*KTOT u16
    u16*   wcat   = (u16*)(ws + off); off += 8192;     // 2*128*64 u16
    u16*   ipk    = (u16*)(ws + off); off += 8192;     // 256*64 u16
    u16*   c1k    = (u16*)(ws + off); off += 8192;     // 2*128*64 u16 (s2w/s3w pack)
    // pad region A so the delta overlay [0, 2359296) never reaches xc
    if (off < 2359296) off = 2359296;
    // --- xc: written k_compip, read k_xdbl4 (dw halo); hend overlays it later. ---
    float* xc     = ws + off; off += 589824;
    u16*   xpk    = (u16*)(ws + off); off += 9216;     // 144*128 u16; read by k_xdbl4
    float* dwk    = ws + off; off += 1280;     // 9*128 tap-major dw weights
    // --- live buffers ---
    float* xca    = ws + off; off += 589824;   // written k_xdbl4 (dw), read scans
    float* zbuf   = ws + off; off += 589824;   // written k_compip, read k_tail
    float* bcbuf  = ws + off; off += 589824;   // written k_xdbl4, read scans
    float* Pend   = ws + off; off += 524288;   // 2048*256
    float* ybuf   = ws + off; off += 2359296;  // scan3 out
    off += 294912;                             // pad (layout stability)
    // overlays
    float* delta  = ws + 0;    // (bk, p_spatial, 128), written k_xdbl4
    float* hend   = xc;        // 524288 <= 589824; xc dead after k_xdbl4, hend written scan1

    k_pp<<<2213, 256, 0, stream>>>(x, pool5, pool9, gmean,
                                   cw, scw, s0w, s1w, ipw, xpw, dww, s2w, s3w,
                                   w8, wcat, ipk, xpk, dwk, c1k);
    k_c1m<<<92, 256, 0, stream>>>(pool5, pool9, gmean, s2g, s2b, s3g, s3b, s4g, s4b, s4w,
                                  c1k, c2cl, c3cl, c4);
    k_cat2<<<cB * 144, 512, 0, stream>>>(x, c4, s0g, s0b, s1g, s1b, scg, scb, cg, cbb,
                                         wcat, c2cl, c3cl, catbf, xbf);
    k_compip<<<cB * cL / 16, 512, 0, stream>>>(catbf, xbf, w8, ipk, xc, zbuf);
    k_xdbl4<<<cB * 144, 1024, 0, stream>>>(xc, dwk, dwb, xpk, dtw, dtb, bcbuf, delta, xca);
    k_scan1<<<64 * NCH, 256, 0, stream>>>(delta, xca, bcbuf, Alog, Pend, hend);
    k_scan3<<<64 * NCH, 256, 0, stream>>>(delta, xca, bcbuf, Alog, Dsv, Pend, hend, ybuf);
    k_tail<<<cB * 576, 256, 0, stream>>>(ybuf, zbuf, lng, lnb, opw, f1w, f1b, f2w, f2b, out);
}